// Round 1
// baseline (265.452 us; speedup 1.0000x reference)
//
#include <hip/hip_runtime.h>
#include <hip/hip_bf16.h>
#include <math.h>

#define Bdim 32
#define Cdim 256
#define Hdim 64
#define Wdim 64
#define HW   (Hdim * Wdim)          // 4096
#define KS   5
#define HID  64
#define E_LAMBDA 1e-4f

__device__ __forceinline__ float sigmoidf(float v) {
    return 1.0f / (1.0f + expf(-v));
}

// ---------------- Kernel 1: per-channel stats + SimAM GAP sum -------------
// One block per (b,c) channel. 256 threads x 16 floats = 4096 elements held
// in registers; one HBM read of x total.
__global__ __launch_bounds__(256) void stats_kernel(
        const float* __restrict__ x,
        float* __restrict__ mean_out,
        float* __restrict__ var_out,
        float* __restrict__ ssum_out) {
    const int bc = blockIdx.x;
    const float4* __restrict__ x4 = (const float4*)(x + (size_t)bc * HW);
    const int t = threadIdx.x;

    float4 v[4];
    float sum = 0.0f, sq = 0.0f;
#pragma unroll
    for (int i = 0; i < 4; ++i) {
        v[i] = x4[t + 256 * i];
        sum += v[i].x + v[i].y + v[i].z + v[i].w;
        sq  += v[i].x * v[i].x + v[i].y * v[i].y
             + v[i].z * v[i].z + v[i].w * v[i].w;
    }

    // wave (64-lane) reduction of both accumulators
#pragma unroll
    for (int off = 32; off > 0; off >>= 1) {
        sum += __shfl_down(sum, off);
        sq  += __shfl_down(sq, off);
    }

    __shared__ float red[8];
    __shared__ float bcast[2];
    const int lane = t & 63;
    const int wid  = t >> 6;
    if (lane == 0) { red[wid] = sum; red[4 + wid] = sq; }
    __syncthreads();
    if (t == 0) {
        const float ts = red[0] + red[1] + red[2] + red[3];
        const float tq = red[4] + red[5] + red[6] + red[7];
        const float mn  = ts * (1.0f / HW);
        const float var = (tq - ts * ts * (1.0f / HW)) * (1.0f / (HW - 1));
        mean_out[bc] = mn;
        var_out[bc]  = var;
        bcast[0] = mn;
        bcast[1] = 0.25f / (var + E_LAMBDA);
    }
    __syncthreads();
    const float mn  = bcast[0];
    const float inv = bcast[1];

    // SimAM: sum over channel of x * sigmoid(d^2/(4(var+eps)) + 0.5)
    float p = 0.0f;
#pragma unroll
    for (int i = 0; i < 4; ++i) {
        float d;
        d = v[i].x - mn; p += v[i].x * sigmoidf(d * d * inv + 0.5f);
        d = v[i].y - mn; p += v[i].y * sigmoidf(d * d * inv + 0.5f);
        d = v[i].z - mn; p += v[i].z * sigmoidf(d * d * inv + 0.5f);
        d = v[i].w - mn; p += v[i].w * sigmoidf(d * d * inv + 0.5f);
    }
#pragma unroll
    for (int off = 32; off > 0; off >>= 1) p += __shfl_down(p, off);
    if (lane == 0) red[wid] = p;
    __syncthreads();
    if (t == 0) ssum_out[bc] = red[0] + red[1] + red[2] + red[3];
}

// ---------------- Kernel 2: ECA conv + gap + MLP -> alpha -----------------
// One block per batch (32 blocks, 256 threads). Tiny.
__global__ __launch_bounds__(256) void gate_mlp_kernel(
        const float* __restrict__ mean_c,
        const float* __restrict__ ssum,
        const float* __restrict__ conv_w,
        const float* __restrict__ w1,
        const float* __restrict__ w2,
        float* __restrict__ eca_out,
        float* __restrict__ alpha_out) {
    const int b = blockIdx.x;
    const int c = threadIdx.x;
    __shared__ float m[Cdim];
    __shared__ float gap[Cdim];
    __shared__ float hid[HID];

    m[c] = mean_c[b * Cdim + c];
    __syncthreads();

    // ECA: cross-correlation over channel dim, zero-padded by 2
    float acc = 0.0f;
#pragma unroll
    for (int k = 0; k < KS; ++k) {
        const int cc = c + k - (KS - 1) / 2;
        const float mv = (cc >= 0 && cc < Cdim) ? m[cc] : 0.0f;
        acc += conv_w[k] * mv;
    }
    const float gate = sigmoidf(acc);
    eca_out[b * Cdim + c] = gate;
    // gap = mean(x_eca + x_simam) = gate*mean + ssum/HW
    gap[c] = gate * m[c] + ssum[b * Cdim + c] * (1.0f / HW);
    __syncthreads();

    if (c < HID) {
        float h = 0.0f;
        for (int i = 0; i < Cdim; ++i) h += gap[i] * w1[c * Cdim + i];
        hid[c] = fmaxf(h, 0.0f);
    }
    __syncthreads();

    float a = 0.0f;
#pragma unroll
    for (int j = 0; j < HID; ++j) a += hid[j] * w2[c * HID + j];
    alpha_out[b * Cdim + c] = sigmoidf(a);
}

// ---------------- Kernel 3: final elementwise blend -----------------------
// out = x * (alpha * s + (1-alpha) * gate),  s = sigmoid(d^2/(4(var+e))+0.5)
__global__ __launch_bounds__(256) void final_kernel(
        const float* __restrict__ x,
        const float* __restrict__ mean_c,
        const float* __restrict__ var_c,
        const float* __restrict__ eca,
        const float* __restrict__ alpha,
        float* __restrict__ out) {
    const int bc = blockIdx.x;
    const float mn  = mean_c[bc];
    const float inv = 0.25f / (var_c[bc] + E_LAMBDA);
    const float g   = eca[bc];
    const float a   = alpha[bc];
    const float one_minus_a_g = (1.0f - a) * g;

    const float4* __restrict__ x4 = (const float4*)(x + (size_t)bc * HW);
    float4* __restrict__ o4 = (float4*)(out + (size_t)bc * HW);
    const int t = threadIdx.x;

#pragma unroll
    for (int i = 0; i < 4; ++i) {
        const float4 v = x4[t + 256 * i];
        float4 r;
        float d;
        d = v.x - mn; r.x = v.x * (a * sigmoidf(d * d * inv + 0.5f) + one_minus_a_g);
        d = v.y - mn; r.y = v.y * (a * sigmoidf(d * d * inv + 0.5f) + one_minus_a_g);
        d = v.z - mn; r.z = v.z * (a * sigmoidf(d * d * inv + 0.5f) + one_minus_a_g);
        d = v.w - mn; r.w = v.w * (a * sigmoidf(d * d * inv + 0.5f) + one_minus_a_g);
        o4[t + 256 * i] = r;
    }
}

extern "C" void kernel_launch(void* const* d_in, const int* in_sizes, int n_in,
                              void* d_out, int out_size, void* d_ws, size_t ws_size,
                              hipStream_t stream) {
    const float* x      = (const float*)d_in[0];
    const float* conv_w = (const float*)d_in[1];
    const float* w1     = (const float*)d_in[2];
    const float* w2     = (const float*)d_in[3];
    float* out = (float*)d_out;

    const int BC = Bdim * Cdim;   // 8192
    float* mean_c = (float*)d_ws;            // [BC]
    float* var_c  = mean_c + BC;             // [BC]
    float* ssum   = var_c + BC;              // [BC]
    float* eca    = ssum + BC;               // [BC]
    float* alpha  = eca + BC;                // [BC]

    stats_kernel<<<BC, 256, 0, stream>>>(x, mean_c, var_c, ssum);
    gate_mlp_kernel<<<Bdim, 256, 0, stream>>>(mean_c, ssum, conv_w, w1, w2, eca, alpha);
    final_kernel<<<BC, 256, 0, stream>>>(x, mean_c, var_c, eca, alpha, out);
}

// Round 3
// 259.909 us; speedup vs baseline: 1.0213x; 1.0213x over previous
//
#include <hip/hip_runtime.h>
#include <hip/hip_bf16.h>
#include <math.h>

#define Bdim 32
#define Cdim 256
#define Hdim 64
#define Wdim 64
#define HW   (Hdim * Wdim)          // 4096
#define KS   5
#define HID  64
#define E_LAMBDA 1e-4f

// native clang vector type — required by __builtin_nontemporal_store
typedef float vfloat4 __attribute__((ext_vector_type(4)));

// fast sigmoid: native v_exp_f32 + v_rcp_f32 (abs err ~1e-6, threshold 8e-2)
__device__ __forceinline__ float sigmoidf(float v) {
    return __builtin_amdgcn_rcpf(1.0f + __expf(-v));
}

// ---------------- Kernel 1: per-channel stats + SimAM GAP sum -------------
// One block per (b,c) channel. 256 threads x 16 floats = 4096 elements held
// in registers; one HBM read of x total (also warms L3 for kernel 3).
__global__ __launch_bounds__(256) void stats_kernel(
        const float* __restrict__ x,
        float* __restrict__ mean_out,
        float* __restrict__ var_out,
        float* __restrict__ ssum_out) {
    const int bc = blockIdx.x;
    const vfloat4* __restrict__ x4 = (const vfloat4*)(x + (size_t)bc * HW);
    const int t = threadIdx.x;

    vfloat4 v[4];
    float sum = 0.0f, sq = 0.0f;
#pragma unroll
    for (int i = 0; i < 4; ++i) {
        v[i] = x4[t + 256 * i];
        sum += v[i].x + v[i].y + v[i].z + v[i].w;
        sq  += v[i].x * v[i].x + v[i].y * v[i].y
             + v[i].z * v[i].z + v[i].w * v[i].w;
    }

    // wave (64-lane) butterfly reduction of both accumulators
#pragma unroll
    for (int off = 32; off > 0; off >>= 1) {
        sum += __shfl_down(sum, off);
        sq  += __shfl_down(sq, off);
    }

    __shared__ float red[8];
    __shared__ float bcast[2];
    const int lane = t & 63;
    const int wid  = t >> 6;
    if (lane == 0) { red[wid] = sum; red[4 + wid] = sq; }
    __syncthreads();
    if (t == 0) {
        const float ts = red[0] + red[1] + red[2] + red[3];
        const float tq = red[4] + red[5] + red[6] + red[7];
        const float mn  = ts * (1.0f / HW);
        const float var = (tq - ts * ts * (1.0f / HW)) * (1.0f / (HW - 1));
        mean_out[bc] = mn;
        var_out[bc]  = var;
        bcast[0] = mn;
        bcast[1] = 0.25f / (var + E_LAMBDA);
    }
    __syncthreads();
    const float mn  = bcast[0];
    const float inv = bcast[1];

    // SimAM: sum over channel of x * sigmoid(d^2/(4(var+eps)) + 0.5)
    float p = 0.0f;
#pragma unroll
    for (int i = 0; i < 4; ++i) {
        float d;
        d = v[i].x - mn; p += v[i].x * sigmoidf(d * d * inv + 0.5f);
        d = v[i].y - mn; p += v[i].y * sigmoidf(d * d * inv + 0.5f);
        d = v[i].z - mn; p += v[i].z * sigmoidf(d * d * inv + 0.5f);
        d = v[i].w - mn; p += v[i].w * sigmoidf(d * d * inv + 0.5f);
    }
#pragma unroll
    for (int off = 32; off > 0; off >>= 1) p += __shfl_down(p, off);
    if (lane == 0) red[wid] = p;
    __syncthreads();
    if (t == 0) ssum_out[bc] = red[0] + red[1] + red[2] + red[3];
}

// ---------------- Kernel 2: ECA conv + gap + MLP -> alpha -----------------
// One block per batch (32 blocks, 256 threads). Tiny.
__global__ __launch_bounds__(256) void gate_mlp_kernel(
        const float* __restrict__ mean_c,
        const float* __restrict__ ssum,
        const float* __restrict__ conv_w,
        const float* __restrict__ w1,
        const float* __restrict__ w2,
        float* __restrict__ eca_out,
        float* __restrict__ alpha_out) {
    const int b = blockIdx.x;
    const int c = threadIdx.x;
    __shared__ float m[Cdim];
    __shared__ float gap[Cdim];
    __shared__ float hid[HID];

    m[c] = mean_c[b * Cdim + c];
    __syncthreads();

    // ECA: cross-correlation over channel dim, zero-padded by 2
    float acc = 0.0f;
#pragma unroll
    for (int k = 0; k < KS; ++k) {
        const int cc = c + k - (KS - 1) / 2;
        const float mv = (cc >= 0 && cc < Cdim) ? m[cc] : 0.0f;
        acc += conv_w[k] * mv;
    }
    const float gate = sigmoidf(acc);
    eca_out[b * Cdim + c] = gate;
    // gap = mean(x_eca + x_simam) = gate*mean + ssum/HW
    gap[c] = gate * m[c] + ssum[b * Cdim + c] * (1.0f / HW);
    __syncthreads();

    if (c < HID) {
        float h = 0.0f;
        for (int i = 0; i < Cdim; ++i) h += gap[i] * w1[c * Cdim + i];
        hid[c] = fmaxf(h, 0.0f);
    }
    __syncthreads();

    float a = 0.0f;
#pragma unroll
    for (int j = 0; j < HID; ++j) a += hid[j] * w2[c * HID + j];
    alpha_out[b * Cdim + c] = sigmoidf(a);
}

// ---------------- Kernel 3: final elementwise blend -----------------------
// out = x * (alpha * s + (1-alpha) * gate),  s = sigmoid(d^2/(4(var+e))+0.5)
// x re-read should hit L3 (warmed by kernel 1); out uses NON-TEMPORAL stores
// so the 128 MiB output stream does not evict x from the 256 MiB L3.
__global__ __launch_bounds__(256) void final_kernel(
        const float* __restrict__ x,
        const float* __restrict__ mean_c,
        const float* __restrict__ var_c,
        const float* __restrict__ eca,
        const float* __restrict__ alpha,
        float* __restrict__ out) {
    const int bc = blockIdx.x;
    const float mn  = mean_c[bc];
    const float inv = 0.25f / (var_c[bc] + E_LAMBDA);
    const float g   = eca[bc];
    const float a   = alpha[bc];
    const float one_minus_a_g = (1.0f - a) * g;

    const vfloat4* __restrict__ x4 = (const vfloat4*)(x + (size_t)bc * HW);
    vfloat4* __restrict__ o4 = (vfloat4*)(out + (size_t)bc * HW);
    const int t = threadIdx.x;

#pragma unroll
    for (int i = 0; i < 4; ++i) {
        const vfloat4 v = x4[t + 256 * i];
        vfloat4 r;
        float d;
        d = v.x - mn; r.x = v.x * (a * sigmoidf(d * d * inv + 0.5f) + one_minus_a_g);
        d = v.y - mn; r.y = v.y * (a * sigmoidf(d * d * inv + 0.5f) + one_minus_a_g);
        d = v.z - mn; r.z = v.z * (a * sigmoidf(d * d * inv + 0.5f) + one_minus_a_g);
        d = v.w - mn; r.w = v.w * (a * sigmoidf(d * d * inv + 0.5f) + one_minus_a_g);
        __builtin_nontemporal_store(r, &o4[t + 256 * i]);
    }
}

extern "C" void kernel_launch(void* const* d_in, const int* in_sizes, int n_in,
                              void* d_out, int out_size, void* d_ws, size_t ws_size,
                              hipStream_t stream) {
    const float* x      = (const float*)d_in[0];
    const float* conv_w = (const float*)d_in[1];
    const float* w1     = (const float*)d_in[2];
    const float* w2     = (const float*)d_in[3];
    float* out = (float*)d_out;

    const int BC = Bdim * Cdim;   // 8192
    float* mean_c = (float*)d_ws;            // [BC]
    float* var_c  = mean_c + BC;             // [BC]
    float* ssum   = var_c + BC;              // [BC]
    float* eca    = ssum + BC;               // [BC]
    float* alpha  = eca + BC;                // [BC]

    stats_kernel<<<BC, 256, 0, stream>>>(x, mean_c, var_c, ssum);
    gate_mlp_kernel<<<Bdim, 256, 0, stream>>>(mean_c, ssum, conv_w, w1, w2, eca, alpha);
    final_kernel<<<BC, 256, 0, stream>>>(x, mean_c, var_c, eca, alpha, out);
}